// Round 7
// baseline (161.340 us; speedup 1.0000x reference)
//
#include <hip/hip_runtime.h>
#include <stdint.h>

#define BB 2
#define HH 32
#define CC 256
#define DD 128
#define GG 2048
#define FF 128
#define NCAT (GG + CC)   // 2304

// ---------------------------------------------------------------------------
// Kernel 1: per-(b,h) stable descending top-G via O(n^2) ranking.
// key = (float_bits << 12) | (4095 - j): values uniform [0,1) => >= 0, raw
// float bits monotone; lower original index wins ties (jax.lax.top_k).
// Writes: new_val/new_idx at rank position, rankws[j] = rank (inverse perm),
// and optionally selws[rank] = j (fallback path only).
// ---------------------------------------------------------------------------
__global__ __launch_bounds__(256) void rank_topk_kernel(
    const float* __restrict__ heap_val, const int* __restrict__ heap_idx,
    const float* __restrict__ score_c, const int* __restrict__ tokens_seen,
    float* __restrict__ out_val, float* __restrict__ out_idx,
    int* __restrict__ rankws, int* __restrict__ selws)
{
    __shared__ uint64_t keys[NCAT];          // 18 KB

    const int blk = blockIdx.x;
    const int bh  = blk / 9;
    const int seg = blk - bh * 9;
    const int tid = threadIdx.x;

    const float* hv = heap_val + (size_t)bh * GG;
    const float* sc = score_c  + (size_t)bh * CC;

    for (int i = tid; i < NCAT; i += 256) {
        uint32_t fb = (i < GG) ? __float_as_uint(hv[i])
                               : __float_as_uint(sc[i - GG]);
        keys[i] = ((uint64_t)fb << 12) | (uint64_t)(4095 - i);
    }
    __syncthreads();

    const int cand = seg * 256 + tid;        // 0..2303
    const uint64_t my = keys[cand];

    int rank = 0;
    const ulonglong2* k2 = (const ulonglong2*)keys;
#pragma unroll 4
    for (int j = 0; j < NCAT / 2; ++j) {     // uniform addr -> LDS broadcast
        ulonglong2 p = k2[j];
        rank += (p.x > my) + (p.y > my);
    }

    rankws[(size_t)bh * NCAT + cand] = rank;  // inverse permutation

    if (rank < GG) {
        const size_t o = (size_t)bh * GG + rank;
        out_val[o] = __uint_as_float((uint32_t)(my >> 12));
        int gidx = (cand < GG) ? heap_idx[(size_t)bh * GG + cand]
                               : (tokens_seen[0] + (cand - GG));
        out_idx[o] = (float)gidx;            // exact (<= 4351)
        if (selws) selws[o] = cand;          // fallback path only
    }
}

// ---------------------------------------------------------------------------
// Kernel 2 (fused, v4): double-buffered LDS + raw s_barrier (lgkmcnt only).
// Sequential-read / scattered-write gather of K/V/FK + partial H and S.
// ONE barrier per tile; global loads/stores are never drained to zero inside
// the loop (the __syncthreads vmcnt(0) drain was the round-4..6 stall).
// ---------------------------------------------------------------------------
__global__ __launch_bounds__(512) void fused_scatter_hsum_db_kernel(
    const float4* __restrict__ K_top, const float4* __restrict__ V_top,
    const float4* __restrict__ FK_top,
    const float4* __restrict__ k_c, const float4* __restrict__ v_c,
    const float4* __restrict__ fk_c,
    const int* __restrict__ rankws,
    float4* __restrict__ oK, float4* __restrict__ oV, float4* __restrict__ oFK,
    float* __restrict__ Hpart, float* __restrict__ Spart, int nseg)
{
    __shared__ float fk_t[2][32][128];     // 32 KB (double-buffered)
    __shared__ float v_t[2][32][128];      // 32 KB

    const int rows_pb = NCAT / nseg;          // 288 (nseg=8) or 576 (nseg=4)
    const int ntiles  = rows_pb / 32;         // 9 or 18
    const int bh  = blockIdx.x / nseg;
    const int seg = blockIdx.x - bh * nseg;
    const int tid = threadIdx.x;
    const int r   = tid >> 4;           // 0..31 row in tile (staging role)
    const int q   = tid & 15;           // float4 col base   (staging role)
    const int tf  = tid >> 5;           // 0..15 f-group (compute role)
    const int td  = tid & 31;           // 0..31 d-group (compute role)

    const long long topQ = (long long)bh * GG * 32;   // quad offsets
    const long long chkQ = (long long)bh * CC * 32;
    const int row0 = seg * rows_pb;
    const int rbase = bh * NCAT + row0;

    float acc[8][4];
#pragma unroll
    for (int a = 0; a < 8; ++a)
#pragma unroll
        for (int b2 = 0; b2 < 4; ++b2) acc[a][b2] = 0.f;
    float4 sA = make_float4(0.f, 0.f, 0.f, 0.f);
    float4 sB = make_float4(0.f, 0.f, 0.f, 0.f);
    const float4 z = make_float4(0.f, 0.f, 0.f, 0.f);

    // ---- prologue: load tile 0 into cur regs, stage buf 0 ----
    int  curRk  = rankws[rbase + r];
    bool curSel = (curRk < GG);
    float4 ck0 = z, ck1 = z, cv0 = z, cv1 = z, cf0 = z, cf1 = z;
    if (curSel) {
        int j = row0 + r;
        const float4* bK = (j < GG) ? K_top  + topQ + (long long)j * 32
                                    : k_c    + chkQ + (long long)(j - GG) * 32;
        const float4* bV = (j < GG) ? V_top  + topQ + (long long)j * 32
                                    : v_c    + chkQ + (long long)(j - GG) * 32;
        const float4* bF = (j < GG) ? FK_top + topQ + (long long)j * 32
                                    : fk_c   + chkQ + (long long)(j - GG) * 32;
        ck0 = bK[q]; ck1 = bK[q + 16];
        cv0 = bV[q]; cv1 = bV[q + 16];
        cf0 = bF[q]; cf1 = bF[q + 16];
    }
    *(float4*)&fk_t[0][r][q * 4]        = cf0;
    *(float4*)&fk_t[0][r][(q + 16) * 4] = cf1;
    *(float4*)&v_t[0][r][q * 4]         = cv0;
    *(float4*)&v_t[0][r][(q + 16) * 4]  = cv1;
    asm volatile("s_waitcnt lgkmcnt(0)" ::: "memory");
    __builtin_amdgcn_s_barrier();
    __builtin_amdgcn_sched_barrier(0);

    int p = 0;
    for (int tile = 0; tile < ntiles; ++tile) {
        const bool more = (tile + 1 < ntiles);

        // 1) issue next tile's sequential loads FIRST (oldest in vmcnt queue)
        int  nRk = 0;  bool nSel = false;
        float4 nk0 = z, nk1 = z, nv0 = z, nv1 = z, nf0 = z, nf1 = z;
        if (more) {
            nRk = rankws[rbase + (tile + 1) * 32 + r];
            nSel = (nRk < GG);
            if (nSel) {
                int j2 = row0 + (tile + 1) * 32 + r;
                const float4* bK = (j2 < GG) ? K_top  + topQ + (long long)j2 * 32
                                             : k_c    + chkQ + (long long)(j2 - GG) * 32;
                const float4* bV = (j2 < GG) ? V_top  + topQ + (long long)j2 * 32
                                             : v_c    + chkQ + (long long)(j2 - GG) * 32;
                const float4* bF = (j2 < GG) ? FK_top + topQ + (long long)j2 * 32
                                             : fk_c   + chkQ + (long long)(j2 - GG) * 32;
                nk0 = bK[q]; nk1 = bK[q + 16];
                nv0 = bV[q]; nv1 = bV[q + 16];
                nf0 = bF[q]; nf1 = bF[q + 16];
            }
        }

        // 2) scatter-store current tile (fire-and-forget; never drained to 0
        //    inside the loop — only counted waits below)
        if (curSel) {
            const long long ob = ((long long)bh * GG + curRk) * 32;
            oFK[ob + q] = cf0;  oFK[ob + q + 16] = cf1;
            oV[ob + q]  = cv0;  oV[ob + q + 16]  = cv1;
            oK[ob + q]  = ck0;  oK[ob + q + 16]  = ck1;
        }

        // 3) S accumulation from current regs
        sA.x += cf0.x; sA.y += cf0.y; sA.z += cf0.z; sA.w += cf0.w;
        sB.x += cf1.x; sB.y += cf1.y; sB.z += cf1.z; sB.w += cf1.w;

        // 4) FMA over buf[p] (long phase; hides the loads and stores above)
#pragma unroll 4
        for (int g = 0; g < 32; ++g) {
            float4 fa0 = *(const float4*)&fk_t[p][g][tf * 8];       // broadcast
            float4 fa1 = *(const float4*)&fk_t[p][g][tf * 8 + 4];
            float4 vvq = *(const float4*)&v_t[p][g][td * 4];        // consecutive
            float fa[8] = {fa0.x, fa0.y, fa0.z, fa0.w, fa1.x, fa1.y, fa1.z, fa1.w};
            float vv[4] = {vvq.x, vvq.y, vvq.z, vvq.w};
#pragma unroll
            for (int a = 0; a < 8; ++a)
#pragma unroll
                for (int b2 = 0; b2 < 4; ++b2)
                    acc[a][b2] += fa[a] * vv[b2];
        }

        // 5) stage next tile into the other buffer; relaxed barrier
        //    (compiler inserts a *counted* vmcnt before the ds_write for the
        //    nxt-reg dependency; stores stay in flight across the barrier)
        if (more) {
            *(float4*)&fk_t[p ^ 1][r][q * 4]        = nf0;
            *(float4*)&fk_t[p ^ 1][r][(q + 16) * 4] = nf1;
            *(float4*)&v_t[p ^ 1][r][q * 4]         = nv0;
            *(float4*)&v_t[p ^ 1][r][(q + 16) * 4]  = nv1;
            asm volatile("s_waitcnt lgkmcnt(0)" ::: "memory");
            __builtin_amdgcn_s_barrier();
            __builtin_amdgcn_sched_barrier(0);
        }

        ck0 = nk0; ck1 = nk1; cv0 = nv0; cv1 = nv1; cf0 = nf0; cf1 = nf1;
        curRk = nRk; curSel = nSel;
        p ^= 1;
    }

    // ---- write partial H (td covers a full 128-float row: coalesced) ----
    float* Hb = Hpart + (long long)blockIdx.x * (FF * DD);
#pragma unroll
    for (int a = 0; a < 8; ++a)
        *(float4*)&Hb[(long long)(tf * 8 + a) * DD + td * 4] =
            make_float4(acc[a][0], acc[a][1], acc[a][2], acc[a][3]);

    // ---- partial S: reduce over 32 staging rows (alias LDS buf 0) ----
    __syncthreads();   // full drain once, before LDS reuse
    float4* sred = (float4*)&fk_t[0][0][0];    // 1024 float4 = 16 KB
    sred[tid]       = sA;
    sred[tid + 512] = sB;
    __syncthreads();
    if (tid < 16) {
        float4 a = make_float4(0.f, 0.f, 0.f, 0.f);
        float4 b = make_float4(0.f, 0.f, 0.f, 0.f);
#pragma unroll
        for (int k = 0; k < 32; ++k) {
            float4 pa = sred[k * 16 + tid];
            float4 pb = sred[k * 16 + tid + 512];
            a.x += pa.x; a.y += pa.y; a.z += pa.z; a.w += pa.w;
            b.x += pb.x; b.y += pb.y; b.z += pb.z; b.w += pb.w;
        }
        float* Sb = Spart + (long long)blockIdx.x * FF;
        *(float4*)&Sb[tid * 4]        = a;
        *(float4*)&Sb[(tid + 16) * 4] = b;
    }
}

// ---------------------------------------------------------------------------
// Kernel 3 (finish): window shift + reduce the nseg H/S partials per bh.
// Roles by blockIdx: [0,4096) window, [4096,5120) H-reduce, [5120,5128) S.
// ---------------------------------------------------------------------------
__global__ __launch_bounds__(256) void finish_kernel(
    const float4* __restrict__ Hpart4, const float4* __restrict__ Spart4,
    const float4* __restrict__ K_win, const float4* __restrict__ V_win,
    const float4* __restrict__ k_c, const float4* __restrict__ v_c,
    float4* __restrict__ oKw, float4* __restrict__ oVw,
    float4* __restrict__ oH, float4* __restrict__ oS, int nseg)
{
    const int b = blockIdx.x;
    const int tid = threadIdx.x;

    if (b < 4096) {
        const int QPA = BB * HH * CC * 32;
        int t = b * 256 + tid;
        int arr = t / QPA;
        int rem = t - arr * QPA;
        int row = rem >> 5;
        int q   = rem & 31;
        int bh  = row >> 8;
        int c   = row & 255;
        const float4* win = arr ? V_win : K_win;
        const float4* chk = arr ? v_c : k_c;
        float4 val = (c < CC - 1)
            ? win[((long long)bh * CC + c + 1) * 32 + q]
            : chk[((long long)bh * CC + (CC - 1)) * 32 + q];
        (arr ? oVw : oKw)[(long long)row * 32 + q] = val;
    } else if (b < 4096 + 1024) {
        int p  = (b - 4096) * 256 + tid;     // 262144 float4 of H
        int bh = p >> 12;
        int off = p & 4095;
        float4 s = make_float4(0.f, 0.f, 0.f, 0.f);
        for (int s4 = 0; s4 < nseg; ++s4) {
            float4 v = Hpart4[(((long long)bh * nseg + s4) << 12) + off];
            s.x += v.x; s.y += v.y; s.z += v.z; s.w += v.w;
        }
        oH[p] = s;
    } else {
        int p = (b - 5120) * 256 + tid;      // 2048 float4 of S
        int bh = p >> 5;
        int off = p & 31;
        float4 s = make_float4(0.f, 0.f, 0.f, 0.f);
        for (int s4 = 0; s4 < nseg; ++s4) {
            float4 v = Spart4[((long long)bh * nseg + s4) * 32 + off];
            s.x += v.x; s.y += v.y; s.z += v.z; s.w += v.w;
        }
        oS[p] = s;
    }
}

// ---------------------------------------------------------------------------
// Fallback kernels (only if ws can't hold the nseg=4 partials).
// ---------------------------------------------------------------------------
__global__ __launch_bounds__(256) void gather_topk_kernel(
    const float4* __restrict__ K_top, const float4* __restrict__ V_top,
    const float4* __restrict__ FK_top,
    const float4* __restrict__ k_c, const float4* __restrict__ v_c,
    const float4* __restrict__ fk_c,
    const int* __restrict__ selws,
    float4* __restrict__ oK, float4* __restrict__ oV, float4* __restrict__ oFK)
{
    const long long ROWQ = (long long)BB * HH * GG * 32;
    long long t = (long long)blockIdx.x * 256 + threadIdx.x;
    int arr = (int)(t / ROWQ);
    long long rem = t - (long long)arr * ROWQ;
    int row = (int)(rem >> 5);
    int q   = (int)(rem & 31);
    int bh  = row >> 11;
    int j   = selws[row];

    const float4* topsrc = (arr == 0) ? K_top : ((arr == 1) ? V_top : FK_top);
    const float4* chksrc = (arr == 0) ? k_c   : ((arr == 1) ? v_c   : fk_c);
    float4*       dst    = (arr == 0) ? oK    : ((arr == 1) ? oV    : oFK);

    float4 val;
    if (j < GG) val = topsrc[((long long)bh * GG + j) * 32 + q];
    else        val = chksrc[((long long)bh * CC + (j - GG)) * 32 + q];
    dst[(long long)row * 32 + q] = val;
}

__global__ __launch_bounds__(256) void window_kernel(
    const float4* __restrict__ K_win, const float4* __restrict__ V_win,
    const float4* __restrict__ k_c, const float4* __restrict__ v_c,
    float4* __restrict__ oKw, float4* __restrict__ oVw)
{
    const int QPA = BB * HH * CC * 32;
    int t = blockIdx.x * 256 + threadIdx.x;
    int arr = t / QPA;
    int rem = t - arr * QPA;
    int row = rem >> 5;
    int q   = rem & 31;
    int bh  = row >> 8;
    int c   = row & 255;

    const float4* win = arr ? V_win : K_win;
    const float4* chk = arr ? v_c : k_c;
    float4 val = (c < CC - 1)
        ? win[((long long)bh * CC + c + 1) * 32 + q]
        : chk[((long long)bh * CC + (CC - 1)) * 32 + q];
    (arr ? oVw : oKw)[(long long)row * 32 + q] = val;
}

__global__ __launch_bounds__(256) void hsum_kernel(
    const float4* __restrict__ FKq, const float4* __restrict__ Vq,
    float* __restrict__ H_out, float* __restrict__ S_out)
{
    __shared__ float fk_t[32][68];
    __shared__ float v_t[32][68];
    __shared__ float4 s4[256];

    const int bx  = blockIdx.x;
    const int bh  = bx >> 2;
    const int fq  = (bx >> 1) & 1;
    const int dq  = bx & 1;
    const int tid = threadIdx.x;
    const int g0 = tid >> 4;
    const int f4 = tid & 15;

    const float4* fkb = FKq + (long long)bh * GG * 32 + fq * 16 + f4;
    const float4* vb  = Vq  + (long long)bh * GG * 32 + dq * 16 + f4;

    float acc[4][4];
#pragma unroll
    for (int a = 0; a < 4; ++a)
#pragma unroll
        for (int b2 = 0; b2 < 4; ++b2) acc[a][b2] = 0.f;
    float4 s_acc = make_float4(0.f, 0.f, 0.f, 0.f);
    const int tf = tid >> 4, td = tid & 15;

    float4 pf_fk0 = fkb[(long long)(g0)      * 32];
    float4 pf_fk1 = fkb[(long long)(g0 + 16) * 32];
    float4 pf_v0  = vb [(long long)(g0)      * 32];
    float4 pf_v1  = vb [(long long)(g0 + 16) * 32];

    for (int c0 = 0; c0 < GG; c0 += 32) {
        __syncthreads();
        *(float4*)&fk_t[g0][f4 * 4]      = pf_fk0;
        *(float4*)&fk_t[g0 + 16][f4 * 4] = pf_fk1;
        *(float4*)&v_t[g0][f4 * 4]       = pf_v0;
        *(float4*)&v_t[g0 + 16][f4 * 4]  = pf_v1;
        s_acc.x += pf_fk0.x + pf_fk1.x;
        s_acc.y += pf_fk0.y + pf_fk1.y;
        s_acc.z += pf_fk0.z + pf_fk1.z;
        s_acc.w += pf_fk0.w + pf_fk1.w;
        __syncthreads();

        if (c0 + 32 < GG) {
            pf_fk0 = fkb[(long long)(c0 + 32 + g0)      * 32];
            pf_fk1 = fkb[(long long)(c0 + 32 + g0 + 16) * 32];
            pf_v0  = vb [(long long)(c0 + 32 + g0)      * 32];
            pf_v1  = vb [(long long)(c0 + 32 + g0 + 16) * 32];
        }

#pragma unroll 4
        for (int g = 0; g < 32; ++g) {
            float fa[4], vv[4];
#pragma unroll
            for (int a = 0; a < 4; ++a) fa[a] = fk_t[g][tf * 4 + a];
#pragma unroll
            for (int b2 = 0; b2 < 4; ++b2) vv[b2] = v_t[g][td * 4 + b2];
#pragma unroll
            for (int a = 0; a < 4; ++a)
#pragma unroll
                for (int b2 = 0; b2 < 4; ++b2)
                    acc[a][b2] += fa[a] * vv[b2];
        }
    }

    float* Hb = H_out + (long long)bh * FF * DD
              + (long long)(fq * 64 + tf * 4) * DD + dq * 64 + td * 4;
#pragma unroll
    for (int a = 0; a < 4; ++a)
        *(float4*)&Hb[(long long)a * DD] =
            make_float4(acc[a][0], acc[a][1], acc[a][2], acc[a][3]);

    s4[tid] = s_acc;
    __syncthreads();
    if (dq == 0 && tid < 16) {
        float4 s = make_float4(0.f, 0.f, 0.f, 0.f);
#pragma unroll
        for (int r = 0; r < 16; ++r) {
            float4 p = s4[r * 16 + tid];
            s.x += p.x; s.y += p.y; s.z += p.z; s.w += p.w;
        }
        S_out[(long long)bh * FF + fq * 64 + tid * 4 + 0] = s.x;
        S_out[(long long)bh * FF + fq * 64 + tid * 4 + 1] = s.y;
        S_out[(long long)bh * FF + fq * 64 + tid * 4 + 2] = s.z;
        S_out[(long long)bh * FF + fq * 64 + tid * 4 + 3] = s.w;
    }
}

// ---------------------------------------------------------------------------
extern "C" void kernel_launch(void* const* d_in, const int* in_sizes, int n_in,
                              void* d_out, int out_size, void* d_ws, size_t ws_size,
                              hipStream_t stream) {
    const float* k_c      = (const float*)d_in[0];
    const float* v_c      = (const float*)d_in[1];
    const float* fk_c     = (const float*)d_in[2];
    const float* score_c  = (const float*)d_in[3];
    const float* K_win    = (const float*)d_in[4];
    const float* V_win    = (const float*)d_in[5];
    const float* K_top    = (const float*)d_in[6];
    const float* V_top    = (const float*)d_in[7];
    const float* FK_top   = (const float*)d_in[8];
    const float* heap_val = (const float*)d_in[9];
    const int*   heap_idx = (const int*)d_in[10];
    const int*   tokens   = (const int*)d_in[11];

    float* out = (float*)d_out;

    const size_t SZ_WIN = (size_t)BB * HH * CC * DD;   // 2,097,152
    const size_t SZ_TOP = (size_t)BB * HH * GG * DD;   // 16,777,216
    const size_t SZ_VAL = (size_t)BB * HH * GG;        //   131,072
    const size_t SZ_H   = (size_t)BB * HH * FF * DD;   // 1,048,576

    float* o_Kwin  = out;
    float* o_Vwin  = o_Kwin  + SZ_WIN;
    float* o_Ktop  = o_Vwin  + SZ_WIN;
    float* o_Vtop  = o_Ktop  + SZ_TOP;
    float* o_FKtop = o_Vtop  + SZ_TOP;
    float* o_val   = o_FKtop + SZ_TOP;
    float* o_idx   = o_val   + SZ_VAL;
    float* o_H     = o_idx   + SZ_VAL;
    float* o_S     = o_H     + SZ_H;

    const size_t rankN = (size_t)BB * HH * NCAT;   // 147,456 ints (576 KB)

    auto need = [&](int ns) {
        return rankN * sizeof(int)
             + (size_t)(BB * HH * ns) * (FF * DD + FF) * sizeof(float);
    };
    int nseg = 0;
    if (ws_size >= need(8)) nseg = 8;
    else if (ws_size >= need(4)) nseg = 4;

    int*   rankws = (int*)d_ws;
    int*   selws  = rankws + rankN;                 // fallback only
    float* Hpart  = (float*)(rankws + rankN);       // fused only
    float* Spart  = Hpart + (size_t)(BB * HH * (nseg ? nseg : 1)) * FF * DD;

    // 1) top-k selection via O(n^2) ranking
    rank_topk_kernel<<<BB * HH * 9, 256, 0, stream>>>(
        heap_val, heap_idx, score_c, tokens, o_val, o_idx,
        rankws, nseg ? nullptr : selws);

    if (nseg) {
        // 2) fused sequential-read gather + partial H/S (double-buffered,
        //    relaxed barriers)
        fused_scatter_hsum_db_kernel<<<BB * HH * nseg, 512, 0, stream>>>(
            (const float4*)K_top, (const float4*)V_top, (const float4*)FK_top,
            (const float4*)k_c, (const float4*)v_c, (const float4*)fk_c,
            rankws, (float4*)o_Ktop, (float4*)o_Vtop, (float4*)o_FKtop,
            Hpart, Spart, nseg);

        // 3) window + partial reduction
        finish_kernel<<<4096 + 1024 + 8, 256, 0, stream>>>(
            (const float4*)Hpart, (const float4*)Spart,
            (const float4*)K_win, (const float4*)V_win,
            (const float4*)k_c, (const float4*)v_c,
            (float4*)o_Kwin, (float4*)o_Vwin, (float4*)o_H, (float4*)o_S, nseg);
    } else {
        // fallback: round-3 structure
        long long nthreads = 3LL * BB * HH * GG * 32;
        gather_topk_kernel<<<(int)(nthreads / 256), 256, 0, stream>>>(
            (const float4*)K_top, (const float4*)V_top, (const float4*)FK_top,
            (const float4*)k_c, (const float4*)v_c, (const float4*)fk_c,
            selws, (float4*)o_Ktop, (float4*)o_Vtop, (float4*)o_FKtop);
        int nthreads2 = 2 * BB * HH * CC * 32;
        window_kernel<<<nthreads2 / 256, 256, 0, stream>>>(
            (const float4*)K_win, (const float4*)V_win,
            (const float4*)k_c, (const float4*)v_c,
            (float4*)o_Kwin, (float4*)o_Vwin);
        hsum_kernel<<<4 * BB * HH, 256, 0, stream>>>(
            (const float4*)o_FKtop, (const float4*)o_Vtop,
            (float*)o_H, (float*)o_S);
    }
}

// Round 8
// 156.799 us; speedup vs baseline: 1.0290x; 1.0290x over previous
//
#include <hip/hip_runtime.h>
#include <stdint.h>

#define BB 2
#define HH 32
#define CC 256
#define DD 128
#define GG 2048
#define FF 128
#define NCAT (GG + CC)   // 2304

// ---------------------------------------------------------------------------
// Kernel 1: per-(b,h) stable descending top-G via O(n^2) ranking.
// key = (float_bits << 12) | (4095 - j): values uniform [0,1) => >= 0, raw
// float bits monotone; lower original index wins ties (jax.lax.top_k).
// Writes: new_val/new_idx at rank position, rankws[j] = rank (inverse perm),
// selws[rank] = j (fallback path only).
// ---------------------------------------------------------------------------
__global__ __launch_bounds__(256) void rank_topk_kernel(
    const float* __restrict__ heap_val, const int* __restrict__ heap_idx,
    const float* __restrict__ score_c, const int* __restrict__ tokens_seen,
    float* __restrict__ out_val, float* __restrict__ out_idx,
    int* __restrict__ rankws, int* __restrict__ selws)
{
    __shared__ uint64_t keys[NCAT];          // 18 KB

    const int blk = blockIdx.x;
    const int bh  = blk / 9;
    const int seg = blk - bh * 9;
    const int tid = threadIdx.x;

    const float* hv = heap_val + (size_t)bh * GG;
    const float* sc = score_c  + (size_t)bh * CC;

    for (int i = tid; i < NCAT; i += 256) {
        uint32_t fb = (i < GG) ? __float_as_uint(hv[i])
                               : __float_as_uint(sc[i - GG]);
        keys[i] = ((uint64_t)fb << 12) | (uint64_t)(4095 - i);
    }
    __syncthreads();

    const int cand = seg * 256 + tid;        // 0..2303
    const uint64_t my = keys[cand];

    int rank = 0;
    const ulonglong2* k2 = (const ulonglong2*)keys;
#pragma unroll 4
    for (int j = 0; j < NCAT / 2; ++j) {     // uniform addr -> LDS broadcast
        ulonglong2 p = k2[j];
        rank += (p.x > my) + (p.y > my);
    }

    rankws[(size_t)bh * NCAT + cand] = rank;  // inverse permutation

    if (rank < GG) {
        const size_t o = (size_t)bh * GG + rank;
        out_val[o] = __uint_as_float((uint32_t)(my >> 12));
        int gidx = (cand < GG) ? heap_idx[(size_t)bh * GG + cand]
                               : (tokens_seen[0] + (cand - GG));
        out_idx[o] = (float)gidx;            // exact (<= 4351)
        if (selws) selws[o] = cand;          // fallback path only
    }
}

// ---------------------------------------------------------------------------
// Kernel 2 (pass1): heterogeneous grid.
//   blocks [0, 64*nseg): fused sequential-read / scattered-write gather of
//     K/V/FK + partial H and S. XCD WRITE-AFFINITY decode: bh = bid & 63,
//     seg = bid >> 6 => all segments of one bh land on XCD bh%8, so one L2
//     accumulates each 1MB destination region's dirty lines.
//   blocks [64*nseg, +2048): sliding-window copy (independent; streams under
//     the gather's spare bandwidth instead of a separate serialized launch).
// ---------------------------------------------------------------------------
__global__ __launch_bounds__(512) void pass1_kernel(
    const float4* __restrict__ K_top, const float4* __restrict__ V_top,
    const float4* __restrict__ FK_top,
    const float4* __restrict__ k_c, const float4* __restrict__ v_c,
    const float4* __restrict__ fk_c,
    const int* __restrict__ rankws,
    const float4* __restrict__ K_win, const float4* __restrict__ V_win,
    float4* __restrict__ oK, float4* __restrict__ oV, float4* __restrict__ oFK,
    float4* __restrict__ oKw, float4* __restrict__ oVw,
    float* __restrict__ Hpart, float* __restrict__ Spart,
    int nseg, int ngather)
{
    __shared__ float fk_t[2][32][128];     // 32 KB (double-buffered)
    __shared__ float v_t[2][32][128];      // 32 KB

    const int tid = threadIdx.x;

    if (blockIdx.x >= ngather) {
        // ---------------- window copy role ----------------
        const int QPA = BB * HH * CC * 32;           // 524288 quads / array
        int t = (blockIdx.x - ngather) * 512 + tid;  // [0, 2*QPA)
        int arr = t / QPA;
        int rem = t - arr * QPA;
        int row = rem >> 5;
        int q   = rem & 31;
        int bh  = row >> 8;
        int c   = row & 255;
        const float4* win = arr ? V_win : K_win;
        const float4* chk = arr ? v_c : k_c;
        float4 val = (c < CC - 1)
            ? win[((long long)bh * CC + c + 1) * 32 + q]
            : chk[((long long)bh * CC + (CC - 1)) * 32 + q];
        (arr ? oVw : oKw)[(long long)row * 32 + q] = val;
        return;
    }

    // ---------------- gather + hsum role ----------------
    const int bh  = blockIdx.x & 63;    // XCD = bh % 8 (write affinity)
    const int seg = blockIdx.x >> 6;    // 0..nseg-1, same XCD for all segs
    const int lgc = bh * nseg + seg;    // logical index for Hpart/Spart

    const int rows_pb = NCAT / nseg;          // 288 (nseg=8) or 576 (nseg=4)
    const int ntiles  = rows_pb / 32;         // 9 or 18
    const int r   = tid >> 4;           // 0..31 row in tile (staging role)
    const int q   = tid & 15;           // float4 col base   (staging role)
    const int tf  = tid >> 5;           // 0..15 f-group (compute role)
    const int td  = tid & 31;           // 0..31 d-group (compute role)

    const long long topQ = (long long)bh * GG * 32;   // quad offsets
    const long long chkQ = (long long)bh * CC * 32;
    const int row0 = seg * rows_pb;
    const int rbase = bh * NCAT + row0;

    float acc[8][4];
#pragma unroll
    for (int a = 0; a < 8; ++a)
#pragma unroll
        for (int b2 = 0; b2 < 4; ++b2) acc[a][b2] = 0.f;
    float4 sA = make_float4(0.f, 0.f, 0.f, 0.f);
    float4 sB = make_float4(0.f, 0.f, 0.f, 0.f);
    const float4 z = make_float4(0.f, 0.f, 0.f, 0.f);

    // ---- prologue: load tile 0 into cur regs, stage buf 0 ----
    int  curRk  = rankws[rbase + r];
    bool curSel = (curRk < GG);
    float4 ck0 = z, ck1 = z, cv0 = z, cv1 = z, cf0 = z, cf1 = z;
    if (curSel) {
        int j = row0 + r;
        const float4* bK = (j < GG) ? K_top  + topQ + (long long)j * 32
                                    : k_c    + chkQ + (long long)(j - GG) * 32;
        const float4* bV = (j < GG) ? V_top  + topQ + (long long)j * 32
                                    : v_c    + chkQ + (long long)(j - GG) * 32;
        const float4* bF = (j < GG) ? FK_top + topQ + (long long)j * 32
                                    : fk_c   + chkQ + (long long)(j - GG) * 32;
        ck0 = bK[q]; ck1 = bK[q + 16];
        cv0 = bV[q]; cv1 = bV[q + 16];
        cf0 = bF[q]; cf1 = bF[q + 16];
    }
    *(float4*)&fk_t[0][r][q * 4]        = cf0;
    *(float4*)&fk_t[0][r][(q + 16) * 4] = cf1;
    *(float4*)&v_t[0][r][q * 4]         = cv0;
    *(float4*)&v_t[0][r][(q + 16) * 4]  = cv1;
    asm volatile("s_waitcnt lgkmcnt(0)" ::: "memory");
    __builtin_amdgcn_s_barrier();
    __builtin_amdgcn_sched_barrier(0);

    int p = 0;
    for (int tile = 0; tile < ntiles; ++tile) {
        const bool more = (tile + 1 < ntiles);

        // 1) issue next tile's sequential loads FIRST
        int  nRk = 0;  bool nSel = false;
        float4 nk0 = z, nk1 = z, nv0 = z, nv1 = z, nf0 = z, nf1 = z;
        if (more) {
            nRk = rankws[rbase + (tile + 1) * 32 + r];
            nSel = (nRk < GG);
            if (nSel) {
                int j2 = row0 + (tile + 1) * 32 + r;
                const float4* bK = (j2 < GG) ? K_top  + topQ + (long long)j2 * 32
                                             : k_c    + chkQ + (long long)(j2 - GG) * 32;
                const float4* bV = (j2 < GG) ? V_top  + topQ + (long long)j2 * 32
                                             : v_c    + chkQ + (long long)(j2 - GG) * 32;
                const float4* bF = (j2 < GG) ? FK_top + topQ + (long long)j2 * 32
                                             : fk_c   + chkQ + (long long)(j2 - GG) * 32;
                nk0 = bK[q]; nk1 = bK[q + 16];
                nv0 = bV[q]; nv1 = bV[q + 16];
                nf0 = bF[q]; nf1 = bF[q + 16];
            }
        }

        // 2) scatter-store current tile (destination region owned by this XCD)
        if (curSel) {
            const long long ob = ((long long)bh * GG + curRk) * 32;
            oFK[ob + q] = cf0;  oFK[ob + q + 16] = cf1;
            oV[ob + q]  = cv0;  oV[ob + q + 16]  = cv1;
            oK[ob + q]  = ck0;  oK[ob + q + 16]  = ck1;
        }

        // 3) S accumulation from current regs
        sA.x += cf0.x; sA.y += cf0.y; sA.z += cf0.z; sA.w += cf0.w;
        sB.x += cf1.x; sB.y += cf1.y; sB.z += cf1.z; sB.w += cf1.w;

        // 4) FMA over buf[p]
#pragma unroll 4
        for (int g = 0; g < 32; ++g) {
            float4 fa0 = *(const float4*)&fk_t[p][g][tf * 8];       // broadcast
            float4 fa1 = *(const float4*)&fk_t[p][g][tf * 8 + 4];
            float4 vvq = *(const float4*)&v_t[p][g][td * 4];        // consecutive
            float fa[8] = {fa0.x, fa0.y, fa0.z, fa0.w, fa1.x, fa1.y, fa1.z, fa1.w};
            float vv[4] = {vvq.x, vvq.y, vvq.z, vvq.w};
#pragma unroll
            for (int a = 0; a < 8; ++a)
#pragma unroll
                for (int b2 = 0; b2 < 4; ++b2)
                    acc[a][b2] += fa[a] * vv[b2];
        }

        // 5) stage next tile into the other buffer; relaxed barrier
        if (more) {
            *(float4*)&fk_t[p ^ 1][r][q * 4]        = nf0;
            *(float4*)&fk_t[p ^ 1][r][(q + 16) * 4] = nf1;
            *(float4*)&v_t[p ^ 1][r][q * 4]         = nv0;
            *(float4*)&v_t[p ^ 1][r][(q + 16) * 4]  = nv1;
            asm volatile("s_waitcnt lgkmcnt(0)" ::: "memory");
            __builtin_amdgcn_s_barrier();
            __builtin_amdgcn_sched_barrier(0);
        }

        ck0 = nk0; ck1 = nk1; cv0 = nv0; cv1 = nv1; cf0 = nf0; cf1 = nf1;
        curRk = nRk; curSel = nSel;
        p ^= 1;
    }

    // ---- write partial H ----
    float* Hb = Hpart + (long long)lgc * (FF * DD);
#pragma unroll
    for (int a = 0; a < 8; ++a)
        *(float4*)&Hb[(long long)(tf * 8 + a) * DD + td * 4] =
            make_float4(acc[a][0], acc[a][1], acc[a][2], acc[a][3]);

    // ---- partial S: reduce over 32 staging rows (alias LDS buf 0) ----
    __syncthreads();   // full drain once, before LDS reuse
    float4* sred = (float4*)&fk_t[0][0][0];    // 1024 float4 = 16 KB
    sred[tid]       = sA;
    sred[tid + 512] = sB;
    __syncthreads();
    if (tid < 16) {
        float4 a = make_float4(0.f, 0.f, 0.f, 0.f);
        float4 b = make_float4(0.f, 0.f, 0.f, 0.f);
#pragma unroll
        for (int k = 0; k < 32; ++k) {
            float4 pa = sred[k * 16 + tid];
            float4 pb = sred[k * 16 + tid + 512];
            a.x += pa.x; a.y += pa.y; a.z += pa.z; a.w += pa.w;
            b.x += pb.x; b.y += pb.y; b.z += pb.z; b.w += pb.w;
        }
        float* Sb = Spart + (long long)lgc * FF;
        *(float4*)&Sb[tid * 4]        = a;
        *(float4*)&Sb[(tid + 16) * 4] = b;
    }
}

// ---------------------------------------------------------------------------
// Kernel 3 (finish): reduce the nseg H/S partials per bh.
// Roles by blockIdx: [0,1024) H-reduce, [1024,1032) S-reduce.
// ---------------------------------------------------------------------------
__global__ __launch_bounds__(256) void finish_kernel(
    const float4* __restrict__ Hpart4, const float4* __restrict__ Spart4,
    float4* __restrict__ oH, float4* __restrict__ oS, int nseg)
{
    const int b = blockIdx.x;
    const int tid = threadIdx.x;

    if (b < 1024) {
        int p  = b * 256 + tid;              // 262144 float4 of H
        int bh = p >> 12;
        int off = p & 4095;
        float4 s = make_float4(0.f, 0.f, 0.f, 0.f);
        for (int s4 = 0; s4 < nseg; ++s4) {
            float4 v = Hpart4[(((long long)bh * nseg + s4) << 12) + off];
            s.x += v.x; s.y += v.y; s.z += v.z; s.w += v.w;
        }
        oH[p] = s;
    } else {
        int p = (b - 1024) * 256 + tid;      // 2048 float4 of S
        int bh = p >> 5;
        int off = p & 31;
        float4 s = make_float4(0.f, 0.f, 0.f, 0.f);
        for (int s4 = 0; s4 < nseg; ++s4) {
            float4 v = Spart4[((long long)bh * nseg + s4) * 32 + off];
            s.x += v.x; s.y += v.y; s.z += v.z; s.w += v.w;
        }
        oS[p] = s;
    }
}

// ---------------------------------------------------------------------------
// Fallback kernels (only if ws can't hold the nseg=4 partials).
// ---------------------------------------------------------------------------
__global__ __launch_bounds__(256) void gather_topk_kernel(
    const float4* __restrict__ K_top, const float4* __restrict__ V_top,
    const float4* __restrict__ FK_top,
    const float4* __restrict__ k_c, const float4* __restrict__ v_c,
    const float4* __restrict__ fk_c,
    const int* __restrict__ selws,
    float4* __restrict__ oK, float4* __restrict__ oV, float4* __restrict__ oFK)
{
    const long long ROWQ = (long long)BB * HH * GG * 32;
    long long t = (long long)blockIdx.x * 256 + threadIdx.x;
    int arr = (int)(t / ROWQ);
    long long rem = t - (long long)arr * ROWQ;
    int row = (int)(rem >> 5);
    int q   = (int)(rem & 31);
    int bh  = row >> 11;
    int j   = selws[row];

    const float4* topsrc = (arr == 0) ? K_top : ((arr == 1) ? V_top : FK_top);
    const float4* chksrc = (arr == 0) ? k_c   : ((arr == 1) ? v_c   : fk_c);
    float4*       dst    = (arr == 0) ? oK    : ((arr == 1) ? oV    : oFK);

    float4 val;
    if (j < GG) val = topsrc[((long long)bh * GG + j) * 32 + q];
    else        val = chksrc[((long long)bh * CC + (j - GG)) * 32 + q];
    dst[(long long)row * 32 + q] = val;
}

__global__ __launch_bounds__(256) void window_kernel(
    const float4* __restrict__ K_win, const float4* __restrict__ V_win,
    const float4* __restrict__ k_c, const float4* __restrict__ v_c,
    float4* __restrict__ oKw, float4* __restrict__ oVw)
{
    const int QPA = BB * HH * CC * 32;
    int t = blockIdx.x * 256 + threadIdx.x;
    int arr = t / QPA;
    int rem = t - arr * QPA;
    int row = rem >> 5;
    int q   = rem & 31;
    int bh  = row >> 8;
    int c   = row & 255;

    const float4* win = arr ? V_win : K_win;
    const float4* chk = arr ? v_c : k_c;
    float4 val = (c < CC - 1)
        ? win[((long long)bh * CC + c + 1) * 32 + q]
        : chk[((long long)bh * CC + (CC - 1)) * 32 + q];
    (arr ? oVw : oKw)[(long long)row * 32 + q] = val;
}

__global__ __launch_bounds__(256) void hsum_kernel(
    const float4* __restrict__ FKq, const float4* __restrict__ Vq,
    float* __restrict__ H_out, float* __restrict__ S_out)
{
    __shared__ float fk_t[32][68];
    __shared__ float v_t[32][68];
    __shared__ float4 s4[256];

    const int bx  = blockIdx.x;
    const int bh  = bx >> 2;
    const int fq  = (bx >> 1) & 1;
    const int dq  = bx & 1;
    const int tid = threadIdx.x;
    const int g0 = tid >> 4;
    const int f4 = tid & 15;

    const float4* fkb = FKq + (long long)bh * GG * 32 + fq * 16 + f4;
    const float4* vb  = Vq  + (long long)bh * GG * 32 + dq * 16 + f4;

    float acc[4][4];
#pragma unroll
    for (int a = 0; a < 4; ++a)
#pragma unroll
        for (int b2 = 0; b2 < 4; ++b2) acc[a][b2] = 0.f;
    float4 s_acc = make_float4(0.f, 0.f, 0.f, 0.f);
    const int tf = tid >> 4, td = tid & 15;

    float4 pf_fk0 = fkb[(long long)(g0)      * 32];
    float4 pf_fk1 = fkb[(long long)(g0 + 16) * 32];
    float4 pf_v0  = vb [(long long)(g0)      * 32];
    float4 pf_v1  = vb [(long long)(g0 + 16) * 32];

    for (int c0 = 0; c0 < GG; c0 += 32) {
        __syncthreads();
        *(float4*)&fk_t[g0][f4 * 4]      = pf_fk0;
        *(float4*)&fk_t[g0 + 16][f4 * 4] = pf_fk1;
        *(float4*)&v_t[g0][f4 * 4]       = pf_v0;
        *(float4*)&v_t[g0 + 16][f4 * 4]  = pf_v1;
        s_acc.x += pf_fk0.x + pf_fk1.x;
        s_acc.y += pf_fk0.y + pf_fk1.y;
        s_acc.z += pf_fk0.z + pf_fk1.z;
        s_acc.w += pf_fk0.w + pf_fk1.w;
        __syncthreads();

        if (c0 + 32 < GG) {
            pf_fk0 = fkb[(long long)(c0 + 32 + g0)      * 32];
            pf_fk1 = fkb[(long long)(c0 + 32 + g0 + 16) * 32];
            pf_v0  = vb [(long long)(c0 + 32 + g0)      * 32];
            pf_v1  = vb [(long long)(c0 + 32 + g0 + 16) * 32];
        }

#pragma unroll 4
        for (int g = 0; g < 32; ++g) {
            float fa[4], vv[4];
#pragma unroll
            for (int a = 0; a < 4; ++a) fa[a] = fk_t[g][tf * 4 + a];
#pragma unroll
            for (int b2 = 0; b2 < 4; ++b2) vv[b2] = v_t[g][td * 4 + b2];
#pragma unroll
            for (int a = 0; a < 4; ++a)
#pragma unroll
                for (int b2 = 0; b2 < 4; ++b2)
                    acc[a][b2] += fa[a] * vv[b2];
        }
    }

    float* Hb = H_out + (long long)bh * FF * DD
              + (long long)(fq * 64 + tf * 4) * DD + dq * 64 + td * 4;
#pragma unroll
    for (int a = 0; a < 4; ++a)
        *(float4*)&Hb[(long long)a * DD] =
            make_float4(acc[a][0], acc[a][1], acc[a][2], acc[a][3]);

    s4[tid] = s_acc;
    __syncthreads();
    if (dq == 0 && tid < 16) {
        float4 s = make_float4(0.f, 0.f, 0.f, 0.f);
#pragma unroll
        for (int r = 0; r < 16; ++r) {
            float4 p = s4[r * 16 + tid];
            s.x += p.x; s.y += p.y; s.z += p.z; s.w += p.w;
        }
        S_out[(long long)bh * FF + fq * 64 + tid * 4 + 0] = s.x;
        S_out[(long long)bh * FF + fq * 64 + tid * 4 + 1] = s.y;
        S_out[(long long)bh * FF + fq * 64 + tid * 4 + 2] = s.z;
        S_out[(long long)bh * FF + fq * 64 + tid * 4 + 3] = s.w;
    }
}

// ---------------------------------------------------------------------------
extern "C" void kernel_launch(void* const* d_in, const int* in_sizes, int n_in,
                              void* d_out, int out_size, void* d_ws, size_t ws_size,
                              hipStream_t stream) {
    const float* k_c      = (const float*)d_in[0];
    const float* v_c      = (const float*)d_in[1];
    const float* fk_c     = (const float*)d_in[2];
    const float* score_c  = (const float*)d_in[3];
    const float* K_win    = (const float*)d_in[4];
    const float* V_win    = (const float*)d_in[5];
    const float* K_top    = (const float*)d_in[6];
    const float* V_top    = (const float*)d_in[7];
    const float* FK_top   = (const float*)d_in[8];
    const float* heap_val = (const float*)d_in[9];
    const int*   heap_idx = (const int*)d_in[10];
    const int*   tokens   = (const int*)d_in[11];

    float* out = (float*)d_out;

    const size_t SZ_WIN = (size_t)BB * HH * CC * DD;   // 2,097,152
    const size_t SZ_TOP = (size_t)BB * HH * GG * DD;   // 16,777,216
    const size_t SZ_VAL = (size_t)BB * HH * GG;        //   131,072
    const size_t SZ_H   = (size_t)BB * HH * FF * DD;   // 1,048,576

    float* o_Kwin  = out;
    float* o_Vwin  = o_Kwin  + SZ_WIN;
    float* o_Ktop  = o_Vwin  + SZ_WIN;
    float* o_Vtop  = o_Ktop  + SZ_TOP;
    float* o_FKtop = o_Vtop  + SZ_TOP;
    float* o_val   = o_FKtop + SZ_TOP;
    float* o_idx   = o_val   + SZ_VAL;
    float* o_H     = o_idx   + SZ_VAL;
    float* o_S     = o_H     + SZ_H;

    const size_t rankN = (size_t)BB * HH * NCAT;   // 147,456 ints (576 KB)

    auto need = [&](int ns) {
        return rankN * sizeof(int)
             + (size_t)(BB * HH * ns) * (FF * DD + FF) * sizeof(float);
    };
    int nseg = 0;
    if (ws_size >= need(8)) nseg = 8;
    else if (ws_size >= need(4)) nseg = 4;

    int*   rankws = (int*)d_ws;
    int*   selws  = rankws + rankN;                 // fallback only
    float* Hpart  = (float*)(rankws + rankN);       // fused only
    float* Spart  = Hpart + (size_t)(BB * HH * (nseg ? nseg : 1)) * FF * DD;

    // 1) top-k selection via O(n^2) ranking
    rank_topk_kernel<<<BB * HH * 9, 256, 0, stream>>>(
        heap_val, heap_idx, score_c, tokens, o_val, o_idx,
        rankws, nseg ? nullptr : selws);

    if (nseg) {
        // 2) pass1: XCD-affine gather + partial H/S, window copy folded in
        const int ngather = BB * HH * nseg;         // 512 (nseg=8)
        const int nwin = (2 * BB * HH * CC * 32) / 512;  // 2048
        pass1_kernel<<<ngather + nwin, 512, 0, stream>>>(
            (const float4*)K_top, (const float4*)V_top, (const float4*)FK_top,
            (const float4*)k_c, (const float4*)v_c, (const float4*)fk_c,
            rankws,
            (const float4*)K_win, (const float4*)V_win,
            (float4*)o_Ktop, (float4*)o_Vtop, (float4*)o_FKtop,
            (float4*)o_Kwin, (float4*)o_Vwin,
            Hpart, Spart, nseg, ngather);

        // 3) H/S partial reduction
        finish_kernel<<<1024 + 8, 256, 0, stream>>>(
            (const float4*)Hpart, (const float4*)Spart,
            (float4*)o_H, (float4*)o_S, nseg);
    } else {
        // fallback: round-3 structure
        long long nthreads = 3LL * BB * HH * GG * 32;
        gather_topk_kernel<<<(int)(nthreads / 256), 256, 0, stream>>>(
            (const float4*)K_top, (const float4*)V_top, (const float4*)FK_top,
            (const float4*)k_c, (const float4*)v_c, (const float4*)fk_c,
            selws, (float4*)o_Ktop, (float4*)o_Vtop, (float4*)o_FKtop);
        int nthreads2 = 2 * BB * HH * CC * 32;
        window_kernel<<<nthreads2 / 256, 256, 0, stream>>>(
            (const float4*)K_win, (const float4*)V_win,
            (const float4*)k_c, (const float4*)v_c,
            (float4*)o_Kwin, (float4*)o_Vwin);
        hsum_kernel<<<4 * BB * HH, 256, 0, stream>>>(
            (const float4*)o_FKtop, (const float4*)o_Vtop,
            (float*)o_H, (float*)o_S);
    }
}

// Round 10
// 154.144 us; speedup vs baseline: 1.0467x; 1.0172x over previous
//
#include <hip/hip_runtime.h>
#include <stdint.h>

#define BB 2
#define HH 32
#define CC 256
#define DD 128
#define GG 2048
#define FF 128
#define NCAT (GG + CC)   // 2304

typedef float nfloat4 __attribute__((ext_vector_type(4)));

__device__ __forceinline__ void nt_store(float4* p, float4 v) {
    nfloat4 nv;
    nv.x = v.x; nv.y = v.y; nv.z = v.z; nv.w = v.w;
    __builtin_nontemporal_store(nv, (nfloat4*)p);
}

// ---------------------------------------------------------------------------
// Kernel 1: per-(b,h) stable descending top-G via O(n^2) ranking.
// key = (float_bits << 12) | (4095 - j): values uniform [0,1) => >= 0, raw
// float bits monotone; lower original index wins ties (jax.lax.top_k).
// ---------------------------------------------------------------------------
__global__ __launch_bounds__(256) void rank_topk_kernel(
    const float* __restrict__ heap_val, const int* __restrict__ heap_idx,
    const float* __restrict__ score_c, const int* __restrict__ tokens_seen,
    float* __restrict__ out_val, float* __restrict__ out_idx,
    int* __restrict__ rankws, int* __restrict__ selws)
{
    __shared__ uint64_t keys[NCAT];          // 18 KB

    const int blk = blockIdx.x;
    const int bh  = blk / 9;
    const int seg = blk - bh * 9;
    const int tid = threadIdx.x;

    const float* hv = heap_val + (size_t)bh * GG;
    const float* sc = score_c  + (size_t)bh * CC;

    for (int i = tid; i < NCAT; i += 256) {
        uint32_t fb = (i < GG) ? __float_as_uint(hv[i])
                               : __float_as_uint(sc[i - GG]);
        keys[i] = ((uint64_t)fb << 12) | (uint64_t)(4095 - i);
    }
    __syncthreads();

    const int cand = seg * 256 + tid;        // 0..2303
    const uint64_t my = keys[cand];

    int rank = 0;
    const ulonglong2* k2 = (const ulonglong2*)keys;
#pragma unroll 4
    for (int j = 0; j < NCAT / 2; ++j) {     // uniform addr -> LDS broadcast
        ulonglong2 p = k2[j];
        rank += (p.x > my) + (p.y > my);
    }

    rankws[(size_t)bh * NCAT + cand] = rank;  // inverse permutation

    if (rank < GG) {
        const size_t o = (size_t)bh * GG + rank;
        out_val[o] = __uint_as_float((uint32_t)(my >> 12));
        int gidx = (cand < GG) ? heap_idx[(size_t)bh * GG + cand]
                               : (tokens_seen[0] + (cand - GG));
        out_idx[o] = (float)gidx;            // exact (<= 4351)
        if (selws) selws[o] = cand;          // fallback path only
    }
}

// ---------------------------------------------------------------------------
// Kernel 2 (pass1): heterogeneous grid.
//   blocks [0, 64*nseg): fused sequential-read / scattered-write gather of
//     K/V/FK + partial H and S. XCD write-affinity decode (bh = bid & 63).
//     ALL final-output stores are NON-TEMPORAL: write data streams past
//     L2/L3 without allocating, so it cannot evict the warm read set.
//   blocks [64*nseg, +2048): sliding-window copy (nt stores too).
// ---------------------------------------------------------------------------
__global__ __launch_bounds__(512) void pass1_kernel(
    const float4* __restrict__ K_top, const float4* __restrict__ V_top,
    const float4* __restrict__ FK_top,
    const float4* __restrict__ k_c, const float4* __restrict__ v_c,
    const float4* __restrict__ fk_c,
    const int* __restrict__ rankws,
    const float4* __restrict__ K_win, const float4* __restrict__ V_win,
    float4* __restrict__ oK, float4* __restrict__ oV, float4* __restrict__ oFK,
    float4* __restrict__ oKw, float4* __restrict__ oVw,
    float* __restrict__ Hpart, float* __restrict__ Spart,
    int nseg, int ngather)
{
    __shared__ float fk_t[2][32][128];     // 32 KB (double-buffered)
    __shared__ float v_t[2][32][128];      // 32 KB

    const int tid = threadIdx.x;

    if (blockIdx.x >= ngather) {
        // ---------------- window copy role ----------------
        const int QPA = BB * HH * CC * 32;           // 524288 quads / array
        int t = (blockIdx.x - ngather) * 512 + tid;  // [0, 2*QPA)
        int arr = t / QPA;
        int rem = t - arr * QPA;
        int row = rem >> 5;
        int q   = rem & 31;
        int bh  = row >> 8;
        int c   = row & 255;
        const float4* win = arr ? V_win : K_win;
        const float4* chk = arr ? v_c : k_c;
        float4 val = (c < CC - 1)
            ? win[((long long)bh * CC + c + 1) * 32 + q]
            : chk[((long long)bh * CC + (CC - 1)) * 32 + q];
        nt_store(&(arr ? oVw : oKw)[(long long)row * 32 + q], val);
        return;
    }

    // ---------------- gather + hsum role ----------------
    const int bh  = blockIdx.x & 63;    // XCD = bh % 8 (write affinity)
    const int seg = blockIdx.x >> 6;    // 0..nseg-1, same XCD for all segs
    const int lgc = bh * nseg + seg;    // logical index for Hpart/Spart

    const int rows_pb = NCAT / nseg;          // 288 (nseg=8) or 576 (nseg=4)
    const int ntiles  = rows_pb / 32;         // 9 or 18
    const int r   = tid >> 4;           // 0..31 row in tile (staging role)
    const int q   = tid & 15;           // float4 col base   (staging role)
    const int tf  = tid >> 5;           // 0..15 f-group (compute role)
    const int td  = tid & 31;           // 0..31 d-group (compute role)

    const long long topQ = (long long)bh * GG * 32;   // quad offsets
    const long long chkQ = (long long)bh * CC * 32;
    const int row0 = seg * rows_pb;
    const int rbase = bh * NCAT + row0;

    float acc[8][4];
#pragma unroll
    for (int a = 0; a < 8; ++a)
#pragma unroll
        for (int b2 = 0; b2 < 4; ++b2) acc[a][b2] = 0.f;
    float4 sA = make_float4(0.f, 0.f, 0.f, 0.f);
    float4 sB = make_float4(0.f, 0.f, 0.f, 0.f);
    const float4 z = make_float4(0.f, 0.f, 0.f, 0.f);

    // ---- prologue: load tile 0 into cur regs, stage buf 0 ----
    int  curRk  = rankws[rbase + r];
    bool curSel = (curRk < GG);
    float4 ck0 = z, ck1 = z, cv0 = z, cv1 = z, cf0 = z, cf1 = z;
    if (curSel) {
        int j = row0 + r;
        const float4* bK = (j < GG) ? K_top  + topQ + (long long)j * 32
                                    : k_c    + chkQ + (long long)(j - GG) * 32;
        const float4* bV = (j < GG) ? V_top  + topQ + (long long)j * 32
                                    : v_c    + chkQ + (long long)(j - GG) * 32;
        const float4* bF = (j < GG) ? FK_top + topQ + (long long)j * 32
                                    : fk_c   + chkQ + (long long)(j - GG) * 32;
        ck0 = bK[q]; ck1 = bK[q + 16];
        cv0 = bV[q]; cv1 = bV[q + 16];
        cf0 = bF[q]; cf1 = bF[q + 16];
    }
    *(float4*)&fk_t[0][r][q * 4]        = cf0;
    *(float4*)&fk_t[0][r][(q + 16) * 4] = cf1;
    *(float4*)&v_t[0][r][q * 4]         = cv0;
    *(float4*)&v_t[0][r][(q + 16) * 4]  = cv1;
    asm volatile("s_waitcnt lgkmcnt(0)" ::: "memory");
    __builtin_amdgcn_s_barrier();
    __builtin_amdgcn_sched_barrier(0);

    int p = 0;
    for (int tile = 0; tile < ntiles; ++tile) {
        const bool more = (tile + 1 < ntiles);

        // 1) issue next tile's sequential loads FIRST
        int  nRk = 0;  bool nSel = false;
        float4 nk0 = z, nk1 = z, nv0 = z, nv1 = z, nf0 = z, nf1 = z;
        if (more) {
            nRk = rankws[rbase + (tile + 1) * 32 + r];
            nSel = (nRk < GG);
            if (nSel) {
                int j2 = row0 + (tile + 1) * 32 + r;
                const float4* bK = (j2 < GG) ? K_top  + topQ + (long long)j2 * 32
                                             : k_c    + chkQ + (long long)(j2 - GG) * 32;
                const float4* bV = (j2 < GG) ? V_top  + topQ + (long long)j2 * 32
                                             : v_c    + chkQ + (long long)(j2 - GG) * 32;
                const float4* bF = (j2 < GG) ? FK_top + topQ + (long long)j2 * 32
                                             : fk_c   + chkQ + (long long)(j2 - GG) * 32;
                nk0 = bK[q]; nk1 = bK[q + 16];
                nv0 = bV[q]; nv1 = bV[q + 16];
                nf0 = bF[q]; nf1 = bF[q + 16];
            }
        }

        // 2) non-temporal scatter-store current tile (write-only data:
        //    stream past L2/L3, don't evict the warm read set)
        if (curSel) {
            const long long ob = ((long long)bh * GG + curRk) * 32;
            nt_store(&oFK[ob + q], cf0);  nt_store(&oFK[ob + q + 16], cf1);
            nt_store(&oV[ob + q],  cv0);  nt_store(&oV[ob + q + 16],  cv1);
            nt_store(&oK[ob + q],  ck0);  nt_store(&oK[ob + q + 16],  ck1);
        }

        // 3) S accumulation from current regs
        sA.x += cf0.x; sA.y += cf0.y; sA.z += cf0.z; sA.w += cf0.w;
        sB.x += cf1.x; sB.y += cf1.y; sB.z += cf1.z; sB.w += cf1.w;

        // 4) FMA over buf[p]
#pragma unroll 4
        for (int g = 0; g < 32; ++g) {
            float4 fa0 = *(const float4*)&fk_t[p][g][tf * 8];       // broadcast
            float4 fa1 = *(const float4*)&fk_t[p][g][tf * 8 + 4];
            float4 vvq = *(const float4*)&v_t[p][g][td * 4];        // consecutive
            float fa[8] = {fa0.x, fa0.y, fa0.z, fa0.w, fa1.x, fa1.y, fa1.z, fa1.w};
            float vv[4] = {vvq.x, vvq.y, vvq.z, vvq.w};
#pragma unroll
            for (int a = 0; a < 8; ++a)
#pragma unroll
                for (int b2 = 0; b2 < 4; ++b2)
                    acc[a][b2] += fa[a] * vv[b2];
        }

        // 5) stage next tile into the other buffer; relaxed barrier
        if (more) {
            *(float4*)&fk_t[p ^ 1][r][q * 4]        = nf0;
            *(float4*)&fk_t[p ^ 1][r][(q + 16) * 4] = nf1;
            *(float4*)&v_t[p ^ 1][r][q * 4]         = nv0;
            *(float4*)&v_t[p ^ 1][r][(q + 16) * 4]  = nv1;
            asm volatile("s_waitcnt lgkmcnt(0)" ::: "memory");
            __builtin_amdgcn_s_barrier();
            __builtin_amdgcn_sched_barrier(0);
        }

        ck0 = nk0; ck1 = nk1; cv0 = nv0; cv1 = nv1; cf0 = nf0; cf1 = nf1;
        curRk = nRk; curSel = nSel;
        p ^= 1;
    }

    // ---- write partial H (re-read by finish: keep cached) ----
    float* Hb = Hpart + (long long)lgc * (FF * DD);
#pragma unroll
    for (int a = 0; a < 8; ++a)
        *(float4*)&Hb[(long long)(tf * 8 + a) * DD + td * 4] =
            make_float4(acc[a][0], acc[a][1], acc[a][2], acc[a][3]);

    // ---- partial S: reduce over 32 staging rows (alias LDS buf 0) ----
    __syncthreads();   // full drain once, before LDS reuse
    float4* sred = (float4*)&fk_t[0][0][0];    // 1024 float4 = 16 KB
    sred[tid]       = sA;
    sred[tid + 512] = sB;
    __syncthreads();
    if (tid < 16) {
        float4 a = make_float4(0.f, 0.f, 0.f, 0.f);
        float4 b = make_float4(0.f, 0.f, 0.f, 0.f);
#pragma unroll
        for (int k = 0; k < 32; ++k) {
            float4 pa = sred[k * 16 + tid];
            float4 pb = sred[k * 16 + tid + 512];
            a.x += pa.x; a.y += pa.y; a.z += pa.z; a.w += pa.w;
            b.x += pb.x; b.y += pb.y; b.z += pb.z; b.w += pb.w;
        }
        float* Sb = Spart + (long long)lgc * FF;
        *(float4*)&Sb[tid * 4]        = a;
        *(float4*)&Sb[(tid + 16) * 4] = b;
    }
}

// ---------------------------------------------------------------------------
// Kernel 3 (finish): reduce the nseg H/S partials per bh.
// Roles by blockIdx: [0,1024) H-reduce, [1024,1032) S-reduce.
// ---------------------------------------------------------------------------
__global__ __launch_bounds__(256) void finish_kernel(
    const float4* __restrict__ Hpart4, const float4* __restrict__ Spart4,
    float4* __restrict__ oH, float4* __restrict__ oS, int nseg)
{
    const int b = blockIdx.x;
    const int tid = threadIdx.x;

    if (b < 1024) {
        int p  = b * 256 + tid;              // 262144 float4 of H
        int bh = p >> 12;
        int off = p & 4095;
        float4 s = make_float4(0.f, 0.f, 0.f, 0.f);
        for (int s4 = 0; s4 < nseg; ++s4) {
            float4 v = Hpart4[(((long long)bh * nseg + s4) << 12) + off];
            s.x += v.x; s.y += v.y; s.z += v.z; s.w += v.w;
        }
        oH[p] = s;
    } else {
        int p = (b - 1024) * 256 + tid;      // 2048 float4 of S
        int bh = p >> 5;
        int off = p & 31;
        float4 s = make_float4(0.f, 0.f, 0.f, 0.f);
        for (int s4 = 0; s4 < nseg; ++s4) {
            float4 v = Spart4[((long long)bh * nseg + s4) * 32 + off];
            s.x += v.x; s.y += v.y; s.z += v.z; s.w += v.w;
        }
        oS[p] = s;
    }
}

// ---------------------------------------------------------------------------
// Fallback kernels (only if ws can't hold the nseg=4 partials).
// ---------------------------------------------------------------------------
__global__ __launch_bounds__(256) void gather_topk_kernel(
    const float4* __restrict__ K_top, const float4* __restrict__ V_top,
    const float4* __restrict__ FK_top,
    const float4* __restrict__ k_c, const float4* __restrict__ v_c,
    const float4* __restrict__ fk_c,
    const int* __restrict__ selws,
    float4* __restrict__ oK, float4* __restrict__ oV, float4* __restrict__ oFK)
{
    const long long ROWQ = (long long)BB * HH * GG * 32;
    long long t = (long long)blockIdx.x * 256 + threadIdx.x;
    int arr = (int)(t / ROWQ);
    long long rem = t - (long long)arr * ROWQ;
    int row = (int)(rem >> 5);
    int q   = (int)(rem & 31);
    int bh  = row >> 11;
    int j   = selws[row];

    const float4* topsrc = (arr == 0) ? K_top : ((arr == 1) ? V_top : FK_top);
    const float4* chksrc = (arr == 0) ? k_c   : ((arr == 1) ? v_c   : fk_c);
    float4*       dst    = (arr == 0) ? oK    : ((arr == 1) ? oV    : oFK);

    float4 val;
    if (j < GG) val = topsrc[((long long)bh * GG + j) * 32 + q];
    else        val = chksrc[((long long)bh * CC + (j - GG)) * 32 + q];
    dst[(long long)row * 32 + q] = val;
}

__global__ __launch_bounds__(256) void window_kernel(
    const float4* __restrict__ K_win, const float4* __restrict__ V_win,
    const float4* __restrict__ k_c, const float4* __restrict__ v_c,
    float4* __restrict__ oKw, float4* __restrict__ oVw)
{
    const int QPA = BB * HH * CC * 32;
    int t = blockIdx.x * 256 + threadIdx.x;
    int arr = t / QPA;
    int rem = t - arr * QPA;
    int row = rem >> 5;
    int q   = rem & 31;
    int bh  = row >> 8;
    int c   = row & 255;

    const float4* win = arr ? V_win : K_win;
    const float4* chk = arr ? v_c : k_c;
    float4 val = (c < CC - 1)
        ? win[((long long)bh * CC + c + 1) * 32 + q]
        : chk[((long long)bh * CC + (CC - 1)) * 32 + q];
    (arr ? oVw : oKw)[(long long)row * 32 + q] = val;
}

__global__ __launch_bounds__(256) void hsum_kernel(
    const float4* __restrict__ FKq, const float4* __restrict__ Vq,
    float* __restrict__ H_out, float* __restrict__ S_out)
{
    __shared__ float fk_t[32][68];
    __shared__ float v_t[32][68];
    __shared__ float4 s4[256];

    const int bx  = blockIdx.x;
    const int bh  = bx >> 2;
    const int fq  = (bx >> 1) & 1;
    const int dq  = bx & 1;
    const int tid = threadIdx.x;
    const int g0 = tid >> 4;
    const int f4 = tid & 15;

    const float4* fkb = FKq + (long long)bh * GG * 32 + fq * 16 + f4;
    const float4* vb  = Vq  + (long long)bh * GG * 32 + dq * 16 + f4;

    float acc[4][4];
#pragma unroll
    for (int a = 0; a < 4; ++a)
#pragma unroll
        for (int b2 = 0; b2 < 4; ++b2) acc[a][b2] = 0.f;
    float4 s_acc = make_float4(0.f, 0.f, 0.f, 0.f);
    const int tf = tid >> 4, td = tid & 15;

    float4 pf_fk0 = fkb[(long long)(g0)      * 32];
    float4 pf_fk1 = fkb[(long long)(g0 + 16) * 32];
    float4 pf_v0  = vb [(long long)(g0)      * 32];
    float4 pf_v1  = vb [(long long)(g0 + 16) * 32];

    for (int c0 = 0; c0 < GG; c0 += 32) {
        __syncthreads();
        *(float4*)&fk_t[g0][f4 * 4]      = pf_fk0;
        *(float4*)&fk_t[g0 + 16][f4 * 4] = pf_fk1;
        *(float4*)&v_t[g0][f4 * 4]       = pf_v0;
        *(float4*)&v_t[g0 + 16][f4 * 4]  = pf_v1;
        s_acc.x += pf_fk0.x + pf_fk1.x;
        s_acc.y += pf_fk0.y + pf_fk1.y;
        s_acc.z += pf_fk0.z + pf_fk1.z;
        s_acc.w += pf_fk0.w + pf_fk1.w;
        __syncthreads();

        if (c0 + 32 < GG) {
            pf_fk0 = fkb[(long long)(c0 + 32 + g0)      * 32];
            pf_fk1 = fkb[(long long)(c0 + 32 + g0 + 16) * 32];
            pf_v0  = vb [(long long)(c0 + 32 + g0)      * 32];
            pf_v1  = vb [(long long)(c0 + 32 + g0 + 16) * 32];
        }

#pragma unroll 4
        for (int g = 0; g < 32; ++g) {
            float fa[4], vv[4];
#pragma unroll
            for (int a = 0; a < 4; ++a) fa[a] = fk_t[g][tf * 4 + a];
#pragma unroll
            for (int b2 = 0; b2 < 4; ++b2) vv[b2] = v_t[g][td * 4 + b2];
#pragma unroll
            for (int a = 0; a < 4; ++a)
#pragma unroll
                for (int b2 = 0; b2 < 4; ++b2)
                    acc[a][b2] += fa[a] * vv[b2];
        }
    }

    float* Hb = H_out + (long long)bh * FF * DD
              + (long long)(fq * 64 + tf * 4) * DD + dq * 64 + td * 4;
#pragma unroll
    for (int a = 0; a < 4; ++a)
        *(float4*)&Hb[(long long)a * DD] =
            make_float4(acc[a][0], acc[a][1], acc[a][2], acc[a][3]);

    s4[tid] = s_acc;
    __syncthreads();
    if (dq == 0 && tid < 16) {
        float4 s = make_float4(0.f, 0.f, 0.f, 0.f);
#pragma unroll
        for (int r = 0; r < 16; ++r) {
            float4 p = s4[r * 16 + tid];
            s.x += p.x; s.y += p.y; s.z += p.z; s.w += p.w;
        }
        S_out[(long long)bh * FF + fq * 64 + tid * 4 + 0] = s.x;
        S_out[(long long)bh * FF + fq * 64 + tid * 4 + 1] = s.y;
        S_out[(long long)bh * FF + fq * 64 + tid * 4 + 2] = s.z;
        S_out[(long long)bh * FF + fq * 64 + tid * 4 + 3] = s.w;
    }
}

// ---------------------------------------------------------------------------
extern "C" void kernel_launch(void* const* d_in, const int* in_sizes, int n_in,
                              void* d_out, int out_size, void* d_ws, size_t ws_size,
                              hipStream_t stream) {
    const float* k_c      = (const float*)d_in[0];
    const float* v_c      = (const float*)d_in[1];
    const float* fk_c     = (const float*)d_in[2];
    const float* score_c  = (const float*)d_in[3];
    const float* K_win    = (const float*)d_in[4];
    const float* V_win    = (const float*)d_in[5];
    const float* K_top    = (const float*)d_in[6];
    const float* V_top    = (const float*)d_in[7];
    const float* FK_top   = (const float*)d_in[8];
    const float* heap_val = (const float*)d_in[9];
    const int*   heap_idx = (const int*)d_in[10];
    const int*   tokens   = (const int*)d_in[11];

    float* out = (float*)d_out;

    const size_t SZ_WIN = (size_t)BB * HH * CC * DD;   // 2,097,152
    const size_t SZ_TOP = (size_t)BB * HH * GG * DD;   // 16,777,216
    const size_t SZ_VAL = (size_t)BB * HH * GG;        //   131,072
    const size_t SZ_H   = (size_t)BB * HH * FF * DD;   // 1,048,576

    float* o_Kwin  = out;
    float* o_Vwin  = o_Kwin  + SZ_WIN;
    float* o_Ktop  = o_Vwin  + SZ_WIN;
    float* o_Vtop  = o_Ktop  + SZ_TOP;
    float* o_FKtop = o_Vtop  + SZ_TOP;
    float* o_val   = o_FKtop + SZ_TOP;
    float* o_idx   = o_val   + SZ_VAL;
    float* o_H     = o_idx   + SZ_VAL;
    float* o_S     = o_H     + SZ_H;

    const size_t rankN = (size_t)BB * HH * NCAT;   // 147,456 ints (576 KB)

    auto need = [&](int ns) {
        return rankN * sizeof(int)
             + (size_t)(BB * HH * ns) * (FF * DD + FF) * sizeof(float);
    };
    int nseg = 0;
    if (ws_size >= need(8)) nseg = 8;
    else if (ws_size >= need(4)) nseg = 4;

    int*   rankws = (int*)d_ws;
    int*   selws  = rankws + rankN;                 // fallback only
    float* Hpart  = (float*)(rankws + rankN);       // fused only
    float* Spart  = Hpart + (size_t)(BB * HH * (nseg ? nseg : 1)) * FF * DD;

    // 1) top-k selection via O(n^2) ranking
    rank_topk_kernel<<<BB * HH * 9, 256, 0, stream>>>(
        heap_val, heap_idx, score_c, tokens, o_val, o_idx,
        rankws, nseg ? nullptr : selws);

    if (nseg) {
        // 2) pass1: XCD-affine gather + partial H/S with NT output stores,
        //    window copy folded in
        const int ngather = BB * HH * nseg;              // 512 (nseg=8)
        const int nwin = (2 * BB * HH * CC * 32) / 512;  // 2048
        pass1_kernel<<<ngather + nwin, 512, 0, stream>>>(
            (const float4*)K_top, (const float4*)V_top, (const float4*)FK_top,
            (const float4*)k_c, (const float4*)v_c, (const float4*)fk_c,
            rankws,
            (const float4*)K_win, (const float4*)V_win,
            (float4*)o_Ktop, (float4*)o_Vtop, (float4*)o_FKtop,
            (float4*)o_Kwin, (float4*)o_Vwin,
            Hpart, Spart, nseg, ngather);

        // 3) H/S partial reduction
        finish_kernel<<<1024 + 8, 256, 0, stream>>>(
            (const float4*)Hpart, (const float4*)Spart,
            (float4*)o_H, (float4*)o_S, nseg);
    } else {
        // fallback: round-3 structure
        long long nthreads = 3LL * BB * HH * GG * 32;
        gather_topk_kernel<<<(int)(nthreads / 256), 256, 0, stream>>>(
            (const float4*)K_top, (const float4*)V_top, (const float4*)FK_top,
            (const float4*)k_c, (const float4*)v_c, (const float4*)fk_c,
            selws, (float4*)o_Ktop, (float4*)o_Vtop, (float4*)o_FKtop);
        int nthreads2 = 2 * BB * HH * CC * 32;
        window_kernel<<<nthreads2 / 256, 256, 0, stream>>>(
            (const float4*)K_win, (const float4*)V_win,
            (const float4*)k_c, (const float4*)v_c,
            (float4*)o_Kwin, (float4*)o_Vwin);
        hsum_kernel<<<4 * BB * HH, 256, 0, stream>>>(
            (const float4*)o_FKtop, (const float4*)o_Vtop,
            (float*)o_H, (float*)o_S);
    }
}